// Round 1
// baseline (605.267 us; speedup 1.0000x reference)
//
#include <hip/hip_runtime.h>
#include <hip/hip_bf16.h>

#define S_ 1024
#define P_ 1024
#define B_ 4
#define E_ 1024
#define J_ 2048
#define H_ 16
#define I_ 64

typedef __bf16 bf16_t;
typedef __bf16 bf16x8 __attribute__((ext_vector_type(8)));
typedef __bf16 bf16x4 __attribute__((ext_vector_type(4)));
typedef float f32x4 __attribute__((ext_vector_type(4)));

#define MFMA16(a, b, c) __builtin_amdgcn_mfma_f32_16x16x32_bf16(a, b, c, 0, 0, 0)

// ---------------- fp32 -> bf16 convert (grid-stride-free exact sizing) ----------------
__global__ __launch_bounds__(256) void cvt_kernel(const float* __restrict__ src,
                                                  bf16_t* __restrict__ dst, int n) {
    int i = (blockIdx.x * 256 + threadIdx.x) * 4;
    if (i < n) {
        float4 v = *(const float4*)(src + i);
        bf16x4 o = {(bf16_t)v.x, (bf16_t)v.y, (bf16_t)v.z, (bf16_t)v.w};
        *(bf16x4*)(dst + i) = o;
    }
}

// ---------------- W (K x N) fp32 -> W^T (N x K) bf16, 32x32 LDS tiles ----------------
__global__ void transpose_cvt(const float* __restrict__ W, bf16_t* __restrict__ Wt,
                              int K, int N) {
    __shared__ float tile[32][33];
    int n0 = blockIdx.x * 32, k0 = blockIdx.y * 32;
    int x = threadIdx.x, y = threadIdx.y;
    for (int i = 0; i < 32; i += 8)
        tile[y + i][x] = W[(size_t)(k0 + y + i) * N + n0 + x];
    __syncthreads();
    for (int i = 0; i < 32; i += 8)
        Wt[(size_t)(n0 + y + i) * K + k0 + x] = (bf16_t)tile[x][y + i];
}

// ---------------- bf16 MFMA GEMM: C(M,N) = A(M,K) @ Bt(N,K)^T ----------------
// 64x64 block tile, 4 waves each 32x32 (2x2 of 16x16), BK=64.
// EPI 0: bf16 store. EPI 1: dual store out0=acc+add0[n], out1=acc+add1[n] (bf16).
// EPI 2: fp32 store outf = acc + add0[m*N+n] (residual).
template <int EPI>
__global__ __launch_bounds__(256) void gemm_bf16(
    const bf16_t* __restrict__ A, const bf16_t* __restrict__ Bt,
    int M, int N, int K,
    bf16_t* __restrict__ out0, bf16_t* __restrict__ out1,
    const float* __restrict__ add0, const float* __restrict__ add1,
    float* __restrict__ outf) {
    __shared__ __attribute__((aligned(16))) bf16_t Al[64][72];
    __shared__ __attribute__((aligned(16))) bf16_t Bl[64][72];
    int tid = threadIdx.x;
    int wave = tid >> 6, lane = tid & 63, quad = lane >> 4, l16 = lane & 15;
    int m0 = blockIdx.y * 64, n0 = blockIdx.x * 64;
    int wm = (wave & 1) * 32, wn = (wave >> 1) * 32;
    f32x4 zero = {0.f, 0.f, 0.f, 0.f};
    f32x4 acc[2][2];
    acc[0][0] = zero; acc[0][1] = zero; acc[1][0] = zero; acc[1][1] = zero;

    for (int k0 = 0; k0 < K; k0 += 64) {
        __syncthreads();
        #pragma unroll
        for (int r = 0; r < 2; r++) {
            int idx = tid + 256 * r;
            int row = idx >> 3, seg = (idx & 7) * 8;
            *(uint4*)&Al[row][seg] = *(const uint4*)&A[(size_t)(m0 + row) * K + k0 + seg];
            *(uint4*)&Bl[row][seg] = *(const uint4*)&Bt[(size_t)(n0 + row) * K + k0 + seg];
        }
        __syncthreads();
        #pragma unroll
        for (int ks = 0; ks < 2; ks++) {
            bf16x8 a0 = *(const bf16x8*)&Al[wm + l16][ks * 32 + quad * 8];
            bf16x8 a1 = *(const bf16x8*)&Al[wm + 16 + l16][ks * 32 + quad * 8];
            bf16x8 b0 = *(const bf16x8*)&Bl[wn + l16][ks * 32 + quad * 8];
            bf16x8 b1 = *(const bf16x8*)&Bl[wn + 16 + l16][ks * 32 + quad * 8];
            acc[0][0] = MFMA16(a0, b0, acc[0][0]);
            acc[0][1] = MFMA16(a0, b1, acc[0][1]);
            acc[1][0] = MFMA16(a1, b0, acc[1][0]);
            acc[1][1] = MFMA16(a1, b1, acc[1][1]);
        }
    }
    #pragma unroll
    for (int i = 0; i < 2; i++)
        #pragma unroll
        for (int j = 0; j < 2; j++)
            #pragma unroll
            for (int reg = 0; reg < 4; reg++) {
                int m = m0 + wm + i * 16 + quad * 4 + reg;
                int n = n0 + wn + j * 16 + l16;
                float v = acc[i][j][reg];
                if (EPI == 0) {
                    out0[(size_t)m * N + n] = (bf16_t)v;
                } else if (EPI == 1) {
                    out0[(size_t)m * N + n] = (bf16_t)(v + add0[n]);
                    out1[(size_t)m * N + n] = (bf16_t)(v + add1[n]);
                } else {
                    outf[(size_t)m * N + n] = v + add0[(size_t)m * N + n];
                }
            }
}

// ---------------- flash attention with TXL relative shift ----------------
// grid (S/64, B*H); block 256 (4 waves x 16 query rows). j-tiles of 32.
// score(s,j) = Qu[s].K[j] + Qv[s].p[j+S-1-s]  (j <= P+s), softmax, @V.
__global__ __launch_bounds__(256) void flash_kernel(
    const bf16_t* __restrict__ qu, const bf16_t* __restrict__ qv,
    const bf16_t* __restrict__ kv, const bf16_t* __restrict__ pm,
    bf16_t* __restrict__ awv) {
    __shared__ __attribute__((aligned(16))) bf16_t Klds[32][72];
    __shared__ __attribute__((aligned(16))) bf16_t Vt[64][40];
    __shared__ __attribute__((aligned(16))) bf16_t Plds[96][72];
    __shared__ __attribute__((aligned(16))) float Elds[4][16][52];
    __shared__ __attribute__((aligned(16))) bf16_t Prob[4][16][40];

    int tid = threadIdx.x;
    int wave = tid >> 6, lane = tid & 63, quad = lane >> 4, l16 = lane & 15;
    int s0 = blockIdx.x * 64;
    int bh = blockIdx.y;
    int b = bh >> 4, h = bh & 15;
    int srow0 = s0 + wave * 16;

    // Q fragments (A-operand: m = l16, k = quad*8+e), held for the whole loop
    const bf16_t* qub = qu + ((size_t)(srow0 + l16) * B_ + b) * 1024 + h * 64 + quad * 8;
    const bf16_t* qvb = qv + ((size_t)(srow0 + l16) * B_ + b) * 1024 + h * 64 + quad * 8;
    bf16x8 aqu0 = *(const bf16x8*)(qub);
    bf16x8 aqu1 = *(const bf16x8*)(qub + 32);
    bf16x8 aqv0 = *(const bf16x8*)(qvb);
    bf16x8 aqv1 = *(const bf16x8*)(qvb + 32);

    f32x4 zero = {0.f, 0.f, 0.f, 0.f};
    f32x4 accO[4];
    #pragma unroll
    for (int ot = 0; ot < 4; ot++) accO[ot] = zero;
    float mrow[4], lrow[4];
    #pragma unroll
    for (int r = 0; r < 4; r++) { mrow[r] = -1e30f; lrow[r] = 0.f; }

    const int nt = (P_ + s0 + 64) >> 5;          // j-tiles of 32
    const int w0u = 960 - s0;                    // union P-window base (+ j0)
    const int woff = 48 - wave * 16;             // per-wave offset into Plds
    const float SCL = 0.125f * 1.44269504088896f; // SCALE * log2(e)

    for (int it = 0; it < nt; it++) {
        int j0 = it * 32;
        __syncthreads();
        {   // cooperative staging
            int jr = tid >> 3, seg = (tid & 7) * 8;
            const bf16_t* src = kv + ((size_t)(j0 + jr) * B_ + b) * 2048 + h * 64;
            *(uint4*)&Klds[jr][seg] = *(const uint4*)(src + seg);
            bf16x8 v8 = *(const bf16x8*)(src + 1024 + seg);
            #pragma unroll
            for (int e = 0; e < 8; e++) Vt[seg + e][jr] = v8[e];   // V transposed
            #pragma unroll
            for (int r = 0; r < 3; r++) {                          // P window, 96 rows
                int idx = tid + 256 * r;
                int pr = idx >> 3, ps = (idx & 7) * 8;
                int prow = w0u + j0 + pr;
                if (prow > J_ - 1) prow = J_ - 1;                  // clamped rows are masked
                *(uint4*)&Plds[pr][ps] = *(const uint4*)(pm + (size_t)prow * 1024 + h * 64 + ps);
            }
        }
        __syncthreads();

        // content scores: 16x32
        f32x4 c0 = zero, c1 = zero;
        {
            bf16x8 b00 = *(const bf16x8*)&Klds[l16][quad * 8];
            bf16x8 b01 = *(const bf16x8*)&Klds[l16][32 + quad * 8];
            bf16x8 b10 = *(const bf16x8*)&Klds[16 + l16][quad * 8];
            bf16x8 b11 = *(const bf16x8*)&Klds[16 + l16][32 + quad * 8];
            c0 = MFMA16(aqu0, b00, c0); c0 = MFMA16(aqu1, b01, c0);
            c1 = MFMA16(aqu0, b10, c1); c1 = MFMA16(aqu1, b11, c1);
        }
        // pos window scores: 16x48 (covers the 47-col shifted band)
        f32x4 e0 = zero, e1 = zero, e2 = zero;
        {
            bf16x8 p00 = *(const bf16x8*)&Plds[woff + l16][quad * 8];
            bf16x8 p01 = *(const bf16x8*)&Plds[woff + l16][32 + quad * 8];
            bf16x8 p10 = *(const bf16x8*)&Plds[woff + 16 + l16][quad * 8];
            bf16x8 p11 = *(const bf16x8*)&Plds[woff + 16 + l16][32 + quad * 8];
            bf16x8 p20 = *(const bf16x8*)&Plds[woff + 32 + l16][quad * 8];
            bf16x8 p21 = *(const bf16x8*)&Plds[woff + 32 + l16][32 + quad * 8];
            e0 = MFMA16(aqv0, p00, e0); e0 = MFMA16(aqv1, p01, e0);
            e1 = MFMA16(aqv0, p10, e1); e1 = MFMA16(aqv1, p11, e1);
            e2 = MFMA16(aqv0, p20, e2); e2 = MFMA16(aqv1, p21, e2);
        }
        // spill E to per-wave LDS for the diagonal shift gather
        #pragma unroll
        for (int reg = 0; reg < 4; reg++) {
            Elds[wave][quad * 4 + reg][l16] = e0[reg];
            Elds[wave][quad * 4 + reg][16 + l16] = e1[reg];
            Elds[wave][quad * 4 + reg][32 + l16] = e2[reg];
        }
        __syncthreads();

        // gather shifted pos, mask, online softmax
        float x0[4], x1[4], al[4];
        #pragma unroll
        for (int reg = 0; reg < 4; reg++) {
            int r = quad * 4 + reg;
            int s = srow0 + r;
            float p0 = Elds[wave][r][l16 + 15 - r];
            float p1 = Elds[wave][r][l16 + 16 + 15 - r];
            float v0 = (c0[reg] + p0) * SCL;
            float v1 = (c1[reg] + p1) * SCL;
            if (j0 + l16 > P_ + s) v0 = -1e30f;
            if (j0 + 16 + l16 > P_ + s) v1 = -1e30f;
            x0[reg] = v0; x1[reg] = v1;
        }
        #pragma unroll
        for (int reg = 0; reg < 4; reg++) {
            float mx = fmaxf(x0[reg], x1[reg]);
            #pragma unroll
            for (int sh = 1; sh < 16; sh <<= 1) mx = fmaxf(mx, __shfl_xor(mx, sh));
            float mnew = fmaxf(mrow[reg], mx);
            float alpha = exp2f(mrow[reg] - mnew);
            float p0 = exp2f(x0[reg] - mnew);
            float p1 = exp2f(x1[reg] - mnew);
            float ps = p0 + p1;
            #pragma unroll
            for (int sh = 1; sh < 16; sh <<= 1) ps += __shfl_xor(ps, sh);
            lrow[reg] = lrow[reg] * alpha + ps;
            mrow[reg] = mnew;
            al[reg] = alpha;
            Prob[wave][quad * 4 + reg][l16] = (bf16_t)p0;
            Prob[wave][quad * 4 + reg][l16 + 16] = (bf16_t)p1;
        }
        #pragma unroll
        for (int ot = 0; ot < 4; ot++)
            #pragma unroll
            for (int reg = 0; reg < 4; reg++) accO[ot][reg] *= al[reg];
        __syncthreads();

        // O += P @ V  (P as A-operand via LDS round-trip; Vt rows are i, cols j)
        bf16x8 pa = *(const bf16x8*)&Prob[wave][l16][quad * 8];
        #pragma unroll
        for (int ot = 0; ot < 4; ot++) {
            bf16x8 bv = *(const bf16x8*)&Vt[ot * 16 + l16][quad * 8];
            accO[ot] = MFMA16(pa, bv, accO[ot]);
        }
    }

    #pragma unroll
    for (int reg = 0; reg < 4; reg++) {
        int r = quad * 4 + reg;
        float inv = 1.0f / lrow[reg];
        size_t rowoff = ((size_t)(srow0 + r) * B_ + b) * 1024 + h * 64;
        #pragma unroll
        for (int ot = 0; ot < 4; ot++)
            awv[rowoff + ot * 16 + l16] = (bf16_t)(accO[ot][reg] * inv);
    }
}

// ---------------- LayerNorm over E=1024, one block per row ----------------
__global__ __launch_bounds__(256) void ln_kernel(const float* __restrict__ x,
                                                 const float* __restrict__ gamma,
                                                 const float* __restrict__ beta,
                                                 float* __restrict__ out) {
    int row = blockIdx.x, tid = threadIdx.x;
    int lane = tid & 63, wave = tid >> 6;
    float4 v = ((const float4*)(x + (size_t)row * 1024))[tid];
    float s = v.x + v.y + v.z + v.w;
    float ss = v.x * v.x + v.y * v.y + v.z * v.z + v.w * v.w;
    #pragma unroll
    for (int sh = 1; sh < 64; sh <<= 1) { s += __shfl_xor(s, sh); ss += __shfl_xor(ss, sh); }
    __shared__ float red[8];
    if (lane == 0) { red[wave] = s; red[4 + wave] = ss; }
    __syncthreads();
    s = red[0] + red[1] + red[2] + red[3];
    ss = red[4] + red[5] + red[6] + red[7];
    float mean = s * (1.f / 1024.f);
    float var = ss * (1.f / 1024.f) - mean * mean;
    float inv = rsqrtf(var + 1e-5f);
    float4 g = ((const float4*)gamma)[tid];
    float4 bt = ((const float4*)beta)[tid];
    float4 o;
    o.x = (v.x - mean) * inv * g.x + bt.x;
    o.y = (v.y - mean) * inv * g.y + bt.y;
    o.z = (v.z - mean) * inv * g.z + bt.z;
    o.w = (v.w - mean) * inv * g.w + bt.w;
    ((float4*)(out + (size_t)row * 1024))[tid] = o;
}

extern "C" void kernel_launch(void* const* d_in, const int* in_sizes, int n_in,
                              void* d_out, int out_size, void* d_ws, size_t ws_size,
                              hipStream_t stream) {
    const float* inputMHA = (const float*)d_in[0];
    const float* posEmb   = (const float*)d_in[1];
    const float* memory   = (const float*)d_in[2];
    const float* u        = (const float*)d_in[3];
    const float* v        = (const float*)d_in[4];
    // d_in[5] = mask: recomputed analytically (j > P + s), never read.
    const float* W_kv     = (const float*)d_in[6];
    const float* W_q      = (const float*)d_in[7];
    const float* W_p      = (const float*)d_in[8];
    const float* W_o      = (const float*)d_in[9];
    const float* gamma    = (const float*)d_in[10];
    const float* beta     = (const float*)d_in[11];
    float* out = (float*)d_out;

    char* ws = (char*)d_ws;
    size_t off = 0;
    auto alloc = [&](size_t bytes) -> void* {
        void* p = ws + off;
        off += (bytes + 255) & ~(size_t)255;
        return p;
    };
    bf16_t* Xbf  = (bf16_t*)alloc((size_t)J_ * B_ * E_ * 2);   // 16 MB
    bf16_t* Wkvt = (bf16_t*)alloc((size_t)2048 * 1024 * 2);
    bf16_t* Wqt  = (bf16_t*)alloc((size_t)1024 * 1024 * 2);
    bf16_t* Wpt  = (bf16_t*)alloc((size_t)1024 * 1024 * 2);
    bf16_t* Wot  = (bf16_t*)alloc((size_t)1024 * 1024 * 2);
    bf16_t* Pemb = (bf16_t*)alloc((size_t)2048 * 1024 * 2);
    bf16_t* kvb  = (bf16_t*)alloc((size_t)8192 * 2048 * 2);    // 32 MB
    bf16_t* qub  = (bf16_t*)alloc((size_t)4096 * 1024 * 2);
    bf16_t* qvb  = (bf16_t*)alloc((size_t)4096 * 1024 * 2);
    bf16_t* pb   = (bf16_t*)alloc((size_t)2048 * 1024 * 2);
    bf16_t* awvb = (bf16_t*)alloc((size_t)4096 * 1024 * 2);
    float*  opre = (float*)alloc((size_t)4096 * 1024 * 4);     // 16 MB

    // converts: X = concat(memory, inputMHA) -> bf16; pos embeddings -> bf16
    cvt_kernel<<<P_ * B_ * E_ / 1024, 256, 0, stream>>>(memory, Xbf, P_ * B_ * E_);
    cvt_kernel<<<S_ * B_ * E_ / 1024, 256, 0, stream>>>(inputMHA, Xbf + (size_t)P_ * B_ * E_,
                                                        S_ * B_ * E_);
    cvt_kernel<<<J_ * E_ / 1024, 256, 0, stream>>>(posEmb, Pemb, J_ * E_);
    // weight transposes (N x K bf16) so GEMM B-fragments read contiguous k
    transpose_cvt<<<dim3(2048 / 32, 1024 / 32), dim3(32, 8), 0, stream>>>(W_kv, Wkvt, 1024, 2048);
    transpose_cvt<<<dim3(1024 / 32, 1024 / 32), dim3(32, 8), 0, stream>>>(W_q, Wqt, 1024, 1024);
    transpose_cvt<<<dim3(1024 / 32, 1024 / 32), dim3(32, 8), 0, stream>>>(W_p, Wpt, 1024, 1024);
    transpose_cvt<<<dim3(1024 / 32, 1024 / 32), dim3(32, 8), 0, stream>>>(W_o, Wot, 1024, 1024);
    // kv = X @ W_kv ; qu/qv = inputMHA @ W_q (+u / +v) ; p = posEmb @ W_p
    gemm_bf16<0><<<dim3(2048 / 64, 8192 / 64), 256, 0, stream>>>(
        Xbf, Wkvt, 8192, 2048, 1024, kvb, nullptr, nullptr, nullptr, nullptr);
    gemm_bf16<1><<<dim3(1024 / 64, 4096 / 64), 256, 0, stream>>>(
        Xbf + (size_t)P_ * B_ * E_, Wqt, 4096, 1024, 1024, qub, qvb, u, v, nullptr);
    gemm_bf16<0><<<dim3(1024 / 64, 2048 / 64), 256, 0, stream>>>(
        Pemb, Wpt, 2048, 1024, 1024, pb, nullptr, nullptr, nullptr, nullptr);
    // attention
    flash_kernel<<<dim3(S_ / 64, B_ * H_), 256, 0, stream>>>(qub, qvb, kvb, pb, awvb);
    // out_pre = inputMHA + awv @ W_o ; then LayerNorm
    gemm_bf16<2><<<dim3(1024 / 64, 4096 / 64), 256, 0, stream>>>(
        awvb, Wot, 4096, 1024, 1024, nullptr, nullptr, inputMHA, nullptr, opre);
    ln_kernel<<<S_ * B_, 256, 0, stream>>>(opre, gamma, beta, out);
}